// Round 9
// baseline (407.394 us; speedup 1.0000x reference)
//
#include <hip/hip_runtime.h>

// ---- problem dims (fixed by setup_inputs) ----
#define N_NODES 131072
#define DIM     128
#define NG      2048
#define HD      512

typedef unsigned short u16;
typedef _Float16 half8 __attribute__((ext_vector_type(8)));
typedef short  short8 __attribute__((ext_vector_type(8)));
typedef float  f32x4  __attribute__((ext_vector_type(4)));

#define SMST 520            // LDS row stride in fp16 (1040 B: 16B-aligned, 260 dw)

// ---- static device scratch (referenced ONLY from device code) ----
__device__ u16   g_wm[(size_t)HD * DIM];          // W_m fp16
__device__ u16   g_wg[(size_t)2048 * 1024];       // [Wih[:,:H]+Whh | Wih[:,H:]] fp16
__device__ u16   g_m16[(size_t)N_NODES * HD];     // m fp16 (134 MB)
__device__ float g_gates[(size_t)NG * 2048];      // 16.8 MB
__device__ u16   g_Acat[(size_t)NG * 1024];       // [h | r] fp16, 4 MB
__device__ float g_c[(size_t)NG * HD];
__device__ float g_h[(size_t)NG * HD];
__device__ int   g_start[NG + 1];
__device__ int   g_isbf16;
__device__ int   g_idx64;

__device__ __forceinline__ float bf2f(u16 u) {
  unsigned v = ((unsigned)u) << 16;
  float f; __builtin_memcpy(&f, &v, 4); return f;
}
__device__ __forceinline__ u16 f2bf(float f) {
  unsigned u; __builtin_memcpy(&u, &f, 4);
  u += 0x7FFFu + ((u >> 16) & 1u);
  return (u16)(u >> 16);
}
__device__ __forceinline__ u16 f2h(float f) {
  _Float16 h = (_Float16)f; u16 u; __builtin_memcpy(&u, &h, 2); return u;
}
__device__ __forceinline__ float rdf(const void* p, int i) {
  return g_isbf16 ? bf2f(((const u16*)p)[i]) : ((const float*)p)[i];
}

#define GLD16(gp, lp) __builtin_amdgcn_global_load_lds(                          \
    (const __attribute__((address_space(1))) void*)(gp),                         \
    (__attribute__((address_space(3))) void*)(lp), 16, 0, 0)

// ---- dtype detection ----
__global__ void k_detect(const void* feat, const void* gi) {
  __shared__ int cnt;
  if (threadIdx.x == 0) cnt = 0;
  __syncthreads();
  u16 u = ((const u16*)feat)[threadIdx.x];
  float v = bf2f(u);
  float a = fabsf(v);
  int ok = (v == v) && a >= 1e-6f && a <= 1e6f;
  atomicAdd(&cnt, ok);
  __syncthreads();
  if (threadIdx.x == 0) {
    g_isbf16 = (cnt >= 230);
    g_idx64 = (((const int*)gi)[N_NODES - 1] == 0);
  }
}

// ---- conversion: W_m -> fp16; build Wg = [Wih_l + Whh | Wih_r] fp16 ----
#define NWP ((size_t)HD * DIM / 2)
#define NWG ((size_t)2048 * 1024 / 2)
__global__ __launch_bounds__(256) void k_cvt_all(const void* wm,
                                                 const void* wih, const void* whh) {
  const int isb = g_isbf16;
  size_t i = (size_t)blockIdx.x * 256 + threadIdx.x;
  if (i < NWP) {
    float v0, v1;
    if (isb) {
      unsigned pr = ((const unsigned*)wm)[i];
      v0 = bf2f((u16)pr); v1 = bf2f((u16)(pr >> 16));
    } else {
      float2 v = ((const float2*)wm)[i];
      v0 = v.x; v1 = v.y;
    }
    ((unsigned*)g_wm)[i] = (unsigned)f2h(v0) | ((unsigned)f2h(v1) << 16);
  } else if (i < NWP + NWG) {
    size_t off = i - NWP;
    int n = (int)(off >> 9), kp = (int)(off & 511);
    int k = kp * 2;
    float v0, v1;
    if (isb) {
      v0 = bf2f(((const u16*)wih)[(size_t)n * 1024 + k]);
      v1 = bf2f(((const u16*)wih)[(size_t)n * 1024 + k + 1]);
      if (k < 512) {
        v0 += bf2f(((const u16*)whh)[(size_t)n * 512 + k]);
        v1 += bf2f(((const u16*)whh)[(size_t)n * 512 + k + 1]);
      }
    } else {
      v0 = ((const float*)wih)[(size_t)n * 1024 + k];
      v1 = ((const float*)wih)[(size_t)n * 1024 + k + 1];
      if (k < 512) {
        v0 += ((const float*)whh)[(size_t)n * 512 + k];
        v1 += ((const float*)whh)[(size_t)n * 512 + k + 1];
      }
    }
    ((unsigned*)g_wg)[off] = (unsigned)f2h(v0) | ((unsigned)f2h(v1) << 16);
  }
}
#define CVT_BLOCKS ((int)((NWP + NWG + 255) / 256))

// ---- zero-init: Acat (1,048,576 dwords) + c (1,048,576 floats) ----
__global__ void k_init() {
  int i = blockIdx.x * 256 + threadIdx.x;            // grid 4096*256
  ((unsigned*)g_Acat)[i] = 0u;
  g_c[i] = 0.f;
}

// ---- per-graph start offsets from sorted graph_index ----
__global__ void k_offsets(const void* giv) {
  int n = blockIdx.x * 256 + threadIdx.x;
  if (n >= N_NODES) return;
  const int idx64 = g_idx64;
  int g = idx64 ? (int)((const long long*)giv)[n] : ((const int*)giv)[n];
  if (n == 0) {
    for (int x = 0; x <= g; ++x) g_start[x] = 0;
  } else {
    int gp = idx64 ? (int)((const long long*)giv)[n - 1] : ((const int*)giv)[n - 1];
    for (int x = gp + 1; x <= g; ++x) g_start[x] = n;
  }
  if (n == N_NODES - 1) {
    for (int x = g + 1; x <= NG; ++x) g_start[x] = N_NODES;
  }
}

// ---- GEMM 1: m = features @ W_m^T + b_m -> fp16
// Block = 32 rows x 512 cols. Wave w computes cols [w*128,(w+1)*128).
// Transposed MFMA -> LDS tile (pad 520) -> full-1KB-row coalesced stores.
__global__ __launch_bounds__(256) void k_gemm_m(const void* __restrict__ feat,
                                                const void* __restrict__ bias) {
  __shared__ u16 sm[32 * SMST];                      // 33.3 KB
  const int t = threadIdx.x, lid = t & 63, w = t >> 6;
  const int rr = lid & 15, quad = lid >> 4;
  const int m0 = blockIdx.x * 32;
  // A-fragments: rows m0+rr and m0+16+rr, full K=128, fp16 in registers
  half8 Ff[4][2];
  if (g_isbf16) {
    const u16* Ap = (const u16*)feat + (size_t)(m0 + rr) * DIM + quad * 8;
#pragma unroll
    for (int k = 0; k < 4; ++k)
#pragma unroll
      for (int i = 0; i < 2; ++i) {
        short8 raw = *(const short8*)(Ap + i * 16 * DIM + k * 32);
        half8 hv;
#pragma unroll
        for (int j = 0; j < 8; ++j) hv[j] = (_Float16)bf2f((u16)raw[j]);
        Ff[k][i] = hv;
      }
  } else {
    const float* Ap = (const float*)feat + (size_t)(m0 + rr) * DIM + quad * 8;
#pragma unroll
    for (int k = 0; k < 4; ++k)
#pragma unroll
      for (int i = 0; i < 2; ++i) {
        float4 v0 = *(const float4*)(Ap + i * 16 * DIM + k * 32);
        float4 v1 = *(const float4*)(Ap + i * 16 * DIM + k * 32 + 4);
        half8 hv;
        hv[0] = (_Float16)v0.x; hv[1] = (_Float16)v0.y;
        hv[2] = (_Float16)v0.z; hv[3] = (_Float16)v0.w;
        hv[4] = (_Float16)v1.x; hv[5] = (_Float16)v1.y;
        hv[6] = (_Float16)v1.z; hv[7] = (_Float16)v1.w;
        Ff[k][i] = hv;
      }
  }
  // 8 n-tiles of 16 cols for this wave; acc[i][j], transposed orientation
  f32x4 acc[2][8] = {};
#pragma unroll
  for (int j = 0; j < 8; ++j) {
    const u16* Bp = g_wm + (size_t)(w * 128 + j * 16 + rr) * DIM + quad * 8;
#pragma unroll
    for (int k = 0; k < 4; ++k) {
      half8 wv = *(const half8*)(Bp + k * 32);
      acc[0][j] = __builtin_amdgcn_mfma_f32_16x16x32_f16(wv, Ff[k][0], acc[0][j], 0, 0, 0);
      acc[1][j] = __builtin_amdgcn_mfma_f32_16x16x32_f16(wv, Ff[k][1], acc[1][j], 0, 0, 0);
    }
  }
  // deposit into LDS: lane holds 4 consecutive cols of row (i*16+rr)
#pragma unroll
  for (int i = 0; i < 2; ++i)
#pragma unroll
    for (int j = 0; j < 8; ++j) {
      const int rowl = i * 16 + rr;
      const int c0 = w * 128 + j * 16 + quad * 4;
      u16 h4[4];
#pragma unroll
      for (int r = 0; r < 4; ++r) h4[r] = f2h(acc[i][j][r] + rdf(bias, c0 + r));
      unsigned lo = (unsigned)h4[0] | ((unsigned)h4[1] << 16);
      unsigned hi = (unsigned)h4[2] | ((unsigned)h4[3] << 16);
      *(uint2*)(sm + rowl * SMST + c0) = make_uint2(lo, hi);
    }
  __syncthreads();
  // store: one full contiguous 1KB row per wave-instruction (ideal HBM writes)
#pragma unroll
  for (int s = 0; s < 8; ++s) {
    const int row = w * 8 + s;
    *(short8*)(g_m16 + (size_t)(m0 + row) * HD + lid * 8) =
        *(const short8*)(sm + row * SMST + lid * 8);
  }
}

// ---- GEMM 2: gates = [h|r] @ Wg^T  (M=2048,N=2048,K=1024), 64x64 tiles ----
__global__ __launch_bounds__(256) void k_gemm_gates() {
  __shared__ u16 As[64 * 64];                        // 8 KB, XOR-swizzled
  __shared__ u16 Bs[64 * 64];                        // 8 KB
  const int t = threadIdx.x, lid = t & 63, w = t >> 6;
  const int m0 = blockIdx.x * 64, n0 = blockIdx.y * 64;
  const int rr = lid & 15, quad = lid >> 4;
  const int rsub = lid >> 3;                         // 0..7
  const int cs = (lid & 7) ^ rsub;                   // swizzled k-chunk
  const int wm = (w >> 1) * 32, wn = (w & 1) * 32;
  f32x4 acc[2][2] = {};
  for (int kt = 0; kt < 16; ++kt) {
    const int k0 = kt * 64;
    GLD16(g_Acat + (size_t)(m0 + w * 16 + rsub) * 1024 + k0 + cs * 8, As + (w * 16) * 64);
    GLD16(g_Acat + (size_t)(m0 + w * 16 + 8 + rsub) * 1024 + k0 + cs * 8, As + (w * 16 + 8) * 64);
    GLD16(g_wg   + (size_t)(n0 + w * 16 + rsub) * 1024 + k0 + cs * 8, Bs + (w * 16) * 64);
    GLD16(g_wg   + (size_t)(n0 + w * 16 + 8 + rsub) * 1024 + k0 + cs * 8, Bs + (w * 16 + 8) * 64);
    __syncthreads();
#pragma unroll
    for (int kk = 0; kk < 2; ++kk) {
      const int qb = kk * 4 + quad;
      const int sw = (qb ^ (rr & 7)) << 3;
      half8 af[2], bfr[2];
#pragma unroll
      for (int i = 0; i < 2; ++i) af[i]  = *(const half8*)(As + (wm + i * 16 + rr) * 64 + sw);
#pragma unroll
      for (int j = 0; j < 2; ++j) bfr[j] = *(const half8*)(Bs + (wn + j * 16 + rr) * 64 + sw);
#pragma unroll
      for (int i = 0; i < 2; ++i)
#pragma unroll
        for (int j = 0; j < 2; ++j)
          acc[i][j] = __builtin_amdgcn_mfma_f32_16x16x32_f16(bfr[j], af[i], acc[i][j], 0, 0, 0);
    }
    __syncthreads();
  }
#pragma unroll
  for (int i = 0; i < 2; ++i)
#pragma unroll
    for (int j = 0; j < 2; ++j) {
      const int row = m0 + wm + i * 16 + rr;
      const int c0 = n0 + wn + j * 16 + quad * 4;
      *(f32x4*)(g_gates + (size_t)row * 2048 + c0) = acc[i][j];
    }
}

// ---- LSTM cell elementwise ----
__global__ __launch_bounds__(256) void k_lstm(const void* __restrict__ b_ih,
                                              const void* __restrict__ b_hh,
                                              void* __restrict__ out) {
  int idx = blockIdx.x * 256 + threadIdx.x;          // NG*HD threads
  int g = idx >> 9, j = idx & 511;
  const float* grow = g_gates + (size_t)g * 2048;
  float xi = grow[j]        + rdf(b_ih, j)        + rdf(b_hh, j);
  float xf = grow[j + 512]  + rdf(b_ih, j + 512)  + rdf(b_hh, j + 512);
  float xg = grow[j + 1024] + rdf(b_ih, j + 1024) + rdf(b_hh, j + 1024);
  float xo = grow[j + 1536] + rdf(b_ih, j + 1536) + rdf(b_hh, j + 1536);
  float si = 1.f / (1.f + __expf(-xi));
  float sf = 1.f / (1.f + __expf(-xf));
  float tg = tanhf(xg);
  float so = 1.f / (1.f + __expf(-xo));
  float cn = sf * g_c[idx] + si * tg;
  float hn = so * tanhf(cn);
  g_c[idx] = cn;
  g_h[idx] = hn;
  g_Acat[(size_t)g * 1024 + j] = f2h(hn);
  if (g_isbf16) ((u16*)out)[(size_t)g * 1024 + j] = f2bf(hn);
  else          ((float*)out)[(size_t)g * 1024 + j] = hn;
}

// ---- attention: single-pass online softmax, 2-node unroll, 1 block/graph ----
__global__ __launch_bounds__(256) void k_attn(void* __restrict__ out) {
  const int g = blockIdx.x;
  const int t = threadIdx.x, lid = t & 63, wid = t >> 6;
  __shared__ float s_m[4], s_l[4];
  __shared__ float s_r[4][HD];
  const int s = g_start[g], e = g_start[g + 1];
  float hreg[8];
  *(float4*)(hreg)     = *(const float4*)(g_h + (size_t)g * HD + lid * 8);
  *(float4*)(hreg + 4) = *(const float4*)(g_h + (size_t)g * HD + lid * 8 + 4);
  float mrun = -3.0e38f, lsum = 0.f;
  float racc[8] = {0.f, 0.f, 0.f, 0.f, 0.f, 0.f, 0.f, 0.f};
  int n = s + wid;
  for (; n + 4 < e; n += 8) {
    half8 hv1 = *(const half8*)(g_m16 + (size_t)n * HD + lid * 8);
    half8 hv2 = *(const half8*)(g_m16 + (size_t)(n + 4) * HD + lid * 8);
    float mv1[8], mv2[8];
    float d1 = 0.f, d2 = 0.f;
#pragma unroll
    for (int j = 0; j < 8; ++j) {
      mv1[j] = (float)hv1[j]; mv2[j] = (float)hv2[j];
      d1 += mv1[j] * hreg[j]; d2 += mv2[j] * hreg[j];
    }
#pragma unroll
    for (int o = 32; o > 0; o >>= 1) {
      d1 += __shfl_xor(d1, o, 64);
      d2 += __shfl_xor(d2, o, 64);
    }
    float mnew = fmaxf(mrun, fmaxf(d1, d2));
    float sc = __expf(mrun - mnew);
    float w1 = __expf(d1 - mnew), w2 = __expf(d2 - mnew);
    lsum = lsum * sc + w1 + w2;
#pragma unroll
    for (int j = 0; j < 8; ++j) racc[j] = racc[j] * sc + w1 * mv1[j] + w2 * mv2[j];
    mrun = mnew;
  }
  if (n < e) {
    half8 hv = *(const half8*)(g_m16 + (size_t)n * HD + lid * 8);
    float mv[8];
    float d = 0.f;
#pragma unroll
    for (int j = 0; j < 8; ++j) { mv[j] = (float)hv[j]; d += mv[j] * hreg[j]; }
#pragma unroll
    for (int o = 32; o > 0; o >>= 1) d += __shfl_xor(d, o, 64);
    float mnew = fmaxf(mrun, d);
    float sc = __expf(mrun - mnew);
    float w = __expf(d - mnew);
    lsum = lsum * sc + w;
#pragma unroll
    for (int j = 0; j < 8; ++j) racc[j] = racc[j] * sc + w * mv[j];
    mrun = mnew;
  }
  if (lid == 0) s_m[wid] = mrun;
  __syncthreads();
  float gmax = fmaxf(fmaxf(s_m[0], s_m[1]), fmaxf(s_m[2], s_m[3]));
  float sc = (mrun > -1.0e38f) ? __expf(mrun - gmax) : 0.f;
#pragma unroll
  for (int j = 0; j < 8; ++j) s_r[wid][lid * 8 + j] = racc[j] * sc;
  if (lid == 0) s_l[wid] = lsum * sc;
  __syncthreads();
  float tot = s_l[0] + s_l[1] + s_l[2] + s_l[3];
  float inv = 1.f / (tot + 1e-7f);
  const int isb = g_isbf16;
  for (int d0 = t; d0 < HD; d0 += 256) {
    float rv = (s_r[0][d0] + s_r[1][d0] + s_r[2][d0] + s_r[3][d0]) * inv;
    g_Acat[(size_t)g * 1024 + 512 + d0] = f2h(rv);
    if (isb) ((u16*)out)[(size_t)g * 1024 + 512 + d0] = f2bf(rv);
    else     ((float*)out)[(size_t)g * 1024 + 512 + d0] = rv;
  }
}

extern "C" void kernel_launch(void* const* d_in, const int* in_sizes, int n_in,
                              void* d_out, int out_size, void* d_ws, size_t ws_size,
                              hipStream_t stream) {
  const void* features = d_in[0];
  const void* gidx     = d_in[1];
  const void* W_m      = d_in[2];
  const void* b_m      = d_in[3];
  const void* W_ih     = d_in[4];
  const void* W_hh     = d_in[5];
  const void* b_ih     = d_in[6];
  const void* b_hh     = d_in[7];

  k_detect<<<1, 256, 0, stream>>>(features, gidx);
  k_cvt_all<<<CVT_BLOCKS, 256, 0, stream>>>(W_m, W_ih, W_hh);
  k_init<<<4096, 256, 0, stream>>>();
  k_offsets<<<N_NODES / 256, 256, 0, stream>>>(gidx);
  k_gemm_m<<<N_NODES / 32, 256, 0, stream>>>(features, b_m);
  for (int loop = 0; loop < 3; ++loop) {
    k_gemm_gates<<<dim3(32, 32), 256, 0, stream>>>();
    k_lstm<<<NG * HD / 256, 256, 0, stream>>>(b_ih, b_hh, d_out);
    k_attn<<<NG, 256, 0, stream>>>(d_out);
  }
}

// Round 10
// 388.661 us; speedup vs baseline: 1.0482x; 1.0482x over previous
//
#include <hip/hip_runtime.h>

// ---- problem dims (fixed by setup_inputs) ----
#define N_NODES 131072
#define DIM     128
#define NG      2048
#define HD      512

typedef unsigned short u16;
typedef _Float16 half8 __attribute__((ext_vector_type(8)));
typedef short  short8 __attribute__((ext_vector_type(8)));
typedef float  f32x4  __attribute__((ext_vector_type(4)));

// ---- static device scratch (referenced ONLY from device code) ----
__device__ u16   g_fb[(size_t)N_NODES * DIM];     // features fp16 (33.5 MB)
__device__ u16   g_wm[(size_t)HD * DIM];          // W_m fp16 (rows j, cols d)
__device__ u16   g_wmT[(size_t)DIM * HD];         // W_m^T fp16 (rows d, cols j)
__device__ u16   g_wg[(size_t)2048 * 1024];       // [Wih[:,:H]+Whh | Wih[:,H:]] fp16
__device__ float g_w2[(size_t)NG * DIM];          // w2 = h @ W_m, fp32 (1 MB)
__device__ float g_gates[(size_t)NG * 2048];      // 16.8 MB
__device__ u16   g_Acat[(size_t)NG * 1024];       // [h | r] fp16, 4 MB
__device__ float g_c[(size_t)NG * HD];
__device__ int   g_start[NG + 1];
__device__ int   g_isbf16;
__device__ int   g_idx64;

__device__ __forceinline__ float bf2f(u16 u) {
  unsigned v = ((unsigned)u) << 16;
  float f; __builtin_memcpy(&f, &v, 4); return f;
}
__device__ __forceinline__ u16 f2bf(float f) {
  unsigned u; __builtin_memcpy(&u, &f, 4);
  u += 0x7FFFu + ((u >> 16) & 1u);
  return (u16)(u >> 16);
}
__device__ __forceinline__ u16 f2h(float f) {
  _Float16 h = (_Float16)f; u16 u; __builtin_memcpy(&u, &h, 2); return u;
}
__device__ __forceinline__ float rdf(const void* p, int i) {
  return g_isbf16 ? bf2f(((const u16*)p)[i]) : ((const float*)p)[i];
}

#define GLD16(gp, lp) __builtin_amdgcn_global_load_lds(                          \
    (const __attribute__((address_space(1))) void*)(gp),                         \
    (__attribute__((address_space(3))) void*)(lp), 16, 0, 0)

// ---- dtype detection ----
__global__ void k_detect(const void* feat, const void* gi) {
  __shared__ int cnt;
  if (threadIdx.x == 0) cnt = 0;
  __syncthreads();
  u16 u = ((const u16*)feat)[threadIdx.x];
  float v = bf2f(u);
  float a = fabsf(v);
  int ok = (v == v) && a >= 1e-6f && a <= 1e6f;
  atomicAdd(&cnt, ok);
  __syncthreads();
  if (threadIdx.x == 0) {
    g_isbf16 = (cnt >= 230);
    g_idx64 = (((const int*)gi)[N_NODES - 1] == 0);
  }
}

// ---- conversions (pair-indexed): features->fp16, W_m->fp16, W_m^T, Wg ----
#define NFP ((size_t)N_NODES * DIM / 2)
#define NWP ((size_t)HD * DIM / 2)
#define NWT ((size_t)DIM * HD / 2)
#define NWG ((size_t)2048 * 1024 / 2)
__global__ __launch_bounds__(256) void k_cvt_all(const void* f, const void* wm,
                                                 const void* wih, const void* whh) {
  const int isb = g_isbf16;
  size_t i = (size_t)blockIdx.x * 256 + threadIdx.x;
  if (i < NFP + NWP) {
    const void* src = (i < NFP) ? f : wm;
    u16* dst = (i < NFP) ? g_fb : g_wm;
    size_t off = (i < NFP) ? i : i - NFP;
    float v0, v1;
    if (isb) {
      unsigned pr = ((const unsigned*)src)[off];
      v0 = bf2f((u16)pr); v1 = bf2f((u16)(pr >> 16));
    } else {
      float2 v = ((const float2*)src)[off];
      v0 = v.x; v1 = v.y;
    }
    ((unsigned*)dst)[off] = (unsigned)f2h(v0) | ((unsigned)f2h(v1) << 16);
  } else if (i < NFP + NWP + NWT) {
    size_t p = i - NFP - NWP;
    int d = (int)(p >> 8), j = (int)(p & 255) * 2;   // wmT[d][j], wmT[d][j+1]
    float v0 = rdf(wm, j * DIM + d);
    float v1 = rdf(wm, (j + 1) * DIM + d);
    ((unsigned*)g_wmT)[(size_t)d * (HD / 2) + (j >> 1)] =
        (unsigned)f2h(v0) | ((unsigned)f2h(v1) << 16);
  } else if (i < NFP + NWP + NWT + NWG) {
    size_t off = i - NFP - NWP - NWT;
    int n = (int)(off >> 9), kp = (int)(off & 511);
    int k = kp * 2;
    float v0 = rdf(wih, n * 1024 + k);
    float v1 = rdf(wih, n * 1024 + k + 1);
    if (k < 512) {
      v0 += rdf(whh, n * 512 + k);
      v1 += rdf(whh, n * 512 + k + 1);
    }
    ((unsigned*)g_wg)[off] = (unsigned)f2h(v0) | ((unsigned)f2h(v1) << 16);
  }
}
#define CVT_BLOCKS ((int)((NFP + NWP + NWT + NWG + 255) / 256))

// ---- zero-init: Acat (1,048,576 dwords) + c (1,048,576 floats) ----
__global__ void k_init() {
  int i = blockIdx.x * 256 + threadIdx.x;            // grid 4096*256
  ((unsigned*)g_Acat)[i] = 0u;
  g_c[i] = 0.f;
}

// ---- per-graph start offsets from sorted graph_index ----
__global__ void k_offsets(const void* giv) {
  int n = blockIdx.x * 256 + threadIdx.x;
  if (n >= N_NODES) return;
  const int idx64 = g_idx64;
  int g = idx64 ? (int)((const long long*)giv)[n] : ((const int*)giv)[n];
  if (n == 0) {
    for (int x = 0; x <= g; ++x) g_start[x] = 0;
  } else {
    int gp = idx64 ? (int)((const long long*)giv)[n - 1] : ((const int*)giv)[n - 1];
    for (int x = gp + 1; x <= g; ++x) g_start[x] = n;
  }
  if (n == N_NODES - 1) {
    for (int x = g + 1; x <= NG; ++x) g_start[x] = N_NODES;
  }
}

// ---- GEMM: gates = [h|r] @ Wg^T  (M=2048,N=2048,K=1024), 64x64 tiles ----
__global__ __launch_bounds__(256) void k_gemm_gates() {
  __shared__ u16 As[64 * 64];                        // 8 KB, XOR-swizzled
  __shared__ u16 Bs[64 * 64];                        // 8 KB
  const int t = threadIdx.x, lid = t & 63, w = t >> 6;
  const int m0 = blockIdx.x * 64, n0 = blockIdx.y * 64;
  const int rr = lid & 15, quad = lid >> 4;
  const int rsub = lid >> 3;                         // 0..7
  const int cs = (lid & 7) ^ rsub;                   // swizzled k-chunk
  const int wm = (w >> 1) * 32, wn = (w & 1) * 32;
  f32x4 acc[2][2] = {};
  for (int kt = 0; kt < 16; ++kt) {
    const int k0 = kt * 64;
    GLD16(g_Acat + (size_t)(m0 + w * 16 + rsub) * 1024 + k0 + cs * 8, As + (w * 16) * 64);
    GLD16(g_Acat + (size_t)(m0 + w * 16 + 8 + rsub) * 1024 + k0 + cs * 8, As + (w * 16 + 8) * 64);
    GLD16(g_wg   + (size_t)(n0 + w * 16 + rsub) * 1024 + k0 + cs * 8, Bs + (w * 16) * 64);
    GLD16(g_wg   + (size_t)(n0 + w * 16 + 8 + rsub) * 1024 + k0 + cs * 8, Bs + (w * 16 + 8) * 64);
    __syncthreads();
#pragma unroll
    for (int kk = 0; kk < 2; ++kk) {
      const int qb = kk * 4 + quad;
      const int sw = (qb ^ (rr & 7)) << 3;
      half8 af[2], bfr[2];
#pragma unroll
      for (int i = 0; i < 2; ++i) af[i]  = *(const half8*)(As + (wm + i * 16 + rr) * 64 + sw);
#pragma unroll
      for (int j = 0; j < 2; ++j) bfr[j] = *(const half8*)(Bs + (wn + j * 16 + rr) * 64 + sw);
#pragma unroll
      for (int i = 0; i < 2; ++i)
#pragma unroll
        for (int j = 0; j < 2; ++j)
          acc[i][j] = __builtin_amdgcn_mfma_f32_16x16x32_f16(bfr[j], af[i], acc[i][j], 0, 0, 0);
    }
    __syncthreads();
  }
#pragma unroll
  for (int i = 0; i < 2; ++i)
#pragma unroll
    for (int j = 0; j < 2; ++j) {
      const int row = m0 + wm + i * 16 + rr;
      const int c0 = n0 + wn + j * 16 + quad * 4;
      *(f32x4*)(g_gates + (size_t)row * 2048 + c0) = acc[i][j];
    }
}

// ---- GEMM: W2 = h @ W_m  (M=2048, N=128, K=512), 64x64 tiles ----
__global__ __launch_bounds__(256) void k_w2() {
  __shared__ u16 As[64 * 64];
  __shared__ u16 Bs[64 * 64];
  const int t = threadIdx.x, lid = t & 63, w = t >> 6;
  const int m0 = blockIdx.x * 64, n0 = blockIdx.y * 64;
  const int rr = lid & 15, quad = lid >> 4;
  const int rsub = lid >> 3;
  const int cs = (lid & 7) ^ rsub;
  const int wm = (w >> 1) * 32, wn = (w & 1) * 32;
  f32x4 acc[2][2] = {};
  for (int kt = 0; kt < 8; ++kt) {
    const int k0 = kt * 64;
    GLD16(g_Acat + (size_t)(m0 + w * 16 + rsub) * 1024 + k0 + cs * 8, As + (w * 16) * 64);
    GLD16(g_Acat + (size_t)(m0 + w * 16 + 8 + rsub) * 1024 + k0 + cs * 8, As + (w * 16 + 8) * 64);
    GLD16(g_wmT  + (size_t)(n0 + w * 16 + rsub) * 512 + k0 + cs * 8, Bs + (w * 16) * 64);
    GLD16(g_wmT  + (size_t)(n0 + w * 16 + 8 + rsub) * 512 + k0 + cs * 8, Bs + (w * 16 + 8) * 64);
    __syncthreads();
#pragma unroll
    for (int kk = 0; kk < 2; ++kk) {
      const int qb = kk * 4 + quad;
      const int sw = (qb ^ (rr & 7)) << 3;
      half8 af[2], bfr[2];
#pragma unroll
      for (int i = 0; i < 2; ++i) af[i]  = *(const half8*)(As + (wm + i * 16 + rr) * 64 + sw);
#pragma unroll
      for (int j = 0; j < 2; ++j) bfr[j] = *(const half8*)(Bs + (wn + j * 16 + rr) * 64 + sw);
#pragma unroll
      for (int i = 0; i < 2; ++i)
#pragma unroll
        for (int j = 0; j < 2; ++j)
          acc[i][j] = __builtin_amdgcn_mfma_f32_16x16x32_f16(bfr[j], af[i], acc[i][j], 0, 0, 0);
    }
    __syncthreads();
  }
#pragma unroll
  for (int i = 0; i < 2; ++i)
#pragma unroll
    for (int j = 0; j < 2; ++j) {
      const int row = m0 + wm + i * 16 + rr;
      const int c0 = n0 + wn + j * 16 + quad * 4;
      *(f32x4*)(g_w2 + (size_t)row * DIM + c0) = acc[i][j];
    }
}

// ---- LSTM cell elementwise ----
__global__ __launch_bounds__(256) void k_lstm(const void* __restrict__ b_ih,
                                              const void* __restrict__ b_hh,
                                              void* __restrict__ out) {
  int idx = blockIdx.x * 256 + threadIdx.x;          // NG*HD threads
  int g = idx >> 9, j = idx & 511;
  const float* grow = g_gates + (size_t)g * 2048;
  float xi = grow[j]        + rdf(b_ih, j)        + rdf(b_hh, j);
  float xf = grow[j + 512]  + rdf(b_ih, j + 512)  + rdf(b_hh, j + 512);
  float xg = grow[j + 1024] + rdf(b_ih, j + 1024) + rdf(b_hh, j + 1024);
  float xo = grow[j + 1536] + rdf(b_ih, j + 1536) + rdf(b_hh, j + 1536);
  float si = 1.f / (1.f + __expf(-xi));
  float sf = 1.f / (1.f + __expf(-xf));
  float tg = tanhf(xg);
  float so = 1.f / (1.f + __expf(-xo));
  float cn = sf * g_c[idx] + si * tg;
  float hn = so * tanhf(cn);
  g_c[idx] = cn;
  g_Acat[(size_t)g * 1024 + j] = f2h(hn);
  if (g_isbf16) ((u16*)out)[(size_t)g * 1024 + j] = f2bf(hn);
  else          ((float*)out)[(size_t)g * 1024 + j] = hn;
}

// ---- attention on features: e_n = f_n . w2_g  (bias term cancels in softmax)
// r = (W_m . sum(w_n f_n)) * inv + (total*inv) * b_m.  One block per graph.
__global__ __launch_bounds__(256) void k_attn(const void* __restrict__ bias,
                                              void* __restrict__ out) {
  const int g = blockIdx.x;
  const int t = threadIdx.x, lid = t & 63, wid = t >> 6;
  const int c = lid & 15;                            // 8-col chunk index
  const int slot = lid >> 4;                         // node slot 0..3
  __shared__ float s_m[4], s_l[4];
  __shared__ float s_s[4][DIM];
  __shared__ float s_tot[DIM];
  const int s = g_start[g], e = g_start[g + 1];
  float w2r[8];
  *(float4*)(w2r)     = *(const float4*)(g_w2 + (size_t)g * DIM + c * 8);
  *(float4*)(w2r + 4) = *(const float4*)(g_w2 + (size_t)g * DIM + c * 8 + 4);
  float mrun = -3.0e38f, lsum = 0.f;
  float racc[8] = {0.f, 0.f, 0.f, 0.f, 0.f, 0.f, 0.f, 0.f};
  for (int nb = s + wid * 4; nb < e; nb += 16) {     // 4 waves x 4 slots
    const int n = nb + slot;
    float fv[8], d;
    if (n < e) {
      half8 hv = *(const half8*)(g_fb + (size_t)n * DIM + c * 8);
      d = 0.f;
#pragma unroll
      for (int j = 0; j < 8; ++j) { fv[j] = (float)hv[j]; d += fv[j] * w2r[j]; }
    } else {
      d = -1.0e30f;                                  // poison: slot inactive
#pragma unroll
      for (int j = 0; j < 8; ++j) fv[j] = 0.f;
    }
    // reduce dot within the 16-lane slot group
#pragma unroll
    for (int o = 1; o < 16; o <<= 1) d += __shfl_xor(d, o, 64);
    // wave max across the 4 slots
    float m4 = fmaxf(d, __shfl_xor(d, 16, 64));
    m4 = fmaxf(m4, __shfl_xor(m4, 32, 64));
    float mnew = fmaxf(mrun, m4);
    float sc = __expf(mrun - mnew);
    float w = __expf(d - mnew);
    lsum = lsum * sc + w;
#pragma unroll
    for (int j = 0; j < 8; ++j) racc[j] = racc[j] * sc + w * fv[j];
    mrun = mnew;
  }
  // combine the 4 slots within the wave
  float lt = lsum + __shfl_xor(lsum, 16, 64);
  lt += __shfl_xor(lt, 32, 64);
#pragma unroll
  for (int j = 0; j < 8; ++j) {
    racc[j] += __shfl_xor(racc[j], 16, 64);
    racc[j] += __shfl_xor(racc[j], 32, 64);
  }
  if (lid == 0) s_m[wid] = mrun;
  __syncthreads();
  float gmax = fmaxf(fmaxf(s_m[0], s_m[1]), fmaxf(s_m[2], s_m[3]));
  float scw = __expf(mrun - gmax);                   // wave-uniform
  if (lid < 16) {
    float4 lo = make_float4(racc[0] * scw, racc[1] * scw, racc[2] * scw, racc[3] * scw);
    float4 hi = make_float4(racc[4] * scw, racc[5] * scw, racc[6] * scw, racc[7] * scw);
    *(float4*)&s_s[wid][c * 8] = lo;
    *(float4*)&s_s[wid][c * 8 + 4] = hi;
  }
  if (lid == 0) s_l[wid] = lt * scw;
  __syncthreads();
  float total = s_l[0] + s_l[1] + s_l[2] + s_l[3];
  float inv = 1.f / (total + 1e-7f);
  float tval = total * inv;                          // sum of attention weights
  if (t < DIM) s_tot[t] = s_s[0][t] + s_s[1][t] + s_s[2][t] + s_s[3][t];
  __syncthreads();
  const int isb = g_isbf16;
  for (int j = t; j < HD; j += 256) {
    const u16* wr = g_wm + (size_t)j * DIM;
    float acc = 0.f;
#pragma unroll
    for (int d8 = 0; d8 < DIM; d8 += 8) {
      half8 wv = *(const half8*)(wr + d8);
#pragma unroll
      for (int jj = 0; jj < 8; ++jj) acc += (float)wv[jj] * s_tot[d8 + jj];
    }
    float rv = acc * inv + tval * rdf(bias, j);
    g_Acat[(size_t)g * 1024 + 512 + j] = f2h(rv);
    if (isb) ((u16*)out)[(size_t)g * 1024 + 512 + j] = f2bf(rv);
    else     ((float*)out)[(size_t)g * 1024 + 512 + j] = rv;
  }
}

extern "C" void kernel_launch(void* const* d_in, const int* in_sizes, int n_in,
                              void* d_out, int out_size, void* d_ws, size_t ws_size,
                              hipStream_t stream) {
  const void* features = d_in[0];
  const void* gidx     = d_in[1];
  const void* W_m      = d_in[2];
  const void* b_m      = d_in[3];
  const void* W_ih     = d_in[4];
  const void* W_hh     = d_in[5];
  const void* b_ih     = d_in[6];
  const void* b_hh     = d_in[7];

  k_detect<<<1, 256, 0, stream>>>(features, gidx);
  k_cvt_all<<<CVT_BLOCKS, 256, 0, stream>>>(features, W_m, W_ih, W_hh);
  k_init<<<4096, 256, 0, stream>>>();
  k_offsets<<<N_NODES / 256, 256, 0, stream>>>(gidx);
  for (int loop = 0; loop < 3; ++loop) {
    k_gemm_gates<<<dim3(32, 32), 256, 0, stream>>>();
    k_lstm<<<NG * HD / 256, 256, 0, stream>>>(b_ih, b_hh, d_out);
    k_w2<<<dim3(32, 2), 256, 0, stream>>>();
    k_attn<<<NG, 256, 0, stream>>>(b_m, d_out);
  }
}

// Round 11
// 293.158 us; speedup vs baseline: 1.3897x; 1.3258x over previous
//
#include <hip/hip_runtime.h>

// ---- problem dims (fixed by setup_inputs) ----
#define N_NODES 131072
#define DIM     128
#define NG      2048
#define HD      512

typedef unsigned short u16;
typedef _Float16 half8 __attribute__((ext_vector_type(8)));
typedef short  short8 __attribute__((ext_vector_type(8)));
typedef float  f32x4  __attribute__((ext_vector_type(4)));

// ---- static device scratch (referenced ONLY from device code) ----
__device__ u16   g_fb[(size_t)N_NODES * DIM];     // features fp16 (33.5 MB)
__device__ u16   g_wm[(size_t)HD * DIM];          // W_m fp16 (rows j, cols d)
__device__ u16   g_wmT[(size_t)DIM * HD];         // W_m^T fp16 (rows d, cols j)
__device__ u16   g_wg[(size_t)2048 * 1024];       // [Wih[:,:H]+Whh | Wih[:,H:]] fp16
__device__ float g_w2[(size_t)NG * DIM];          // w2 = h @ W_m, fp32 (1 MB)
__device__ u16   g_sp[(size_t)NG * DIM];          // S' = sum a_n f_n, fp16
__device__ float g_tp[NG];                        // t' = sum a_n
__device__ float g_gates[(size_t)NG * 2048];      // 16.8 MB
__device__ u16   g_Acat[(size_t)NG * 1024];       // [h | r] fp16, 4 MB
__device__ float g_c[(size_t)NG * HD];
__device__ int   g_start[NG + 1];
__device__ int   g_isbf16;
__device__ int   g_idx64;

__device__ __forceinline__ float bf2f(u16 u) {
  unsigned v = ((unsigned)u) << 16;
  float f; __builtin_memcpy(&f, &v, 4); return f;
}
__device__ __forceinline__ u16 f2bf(float f) {
  unsigned u; __builtin_memcpy(&u, &f, 4);
  u += 0x7FFFu + ((u >> 16) & 1u);
  return (u16)(u >> 16);
}
__device__ __forceinline__ u16 f2h(float f) {
  _Float16 h = (_Float16)f; u16 u; __builtin_memcpy(&u, &h, 2); return u;
}
__device__ __forceinline__ float rdf(const void* p, int i) {
  return g_isbf16 ? bf2f(((const u16*)p)[i]) : ((const float*)p)[i];
}

#define GLD16(gp, lp) __builtin_amdgcn_global_load_lds(                          \
    (const __attribute__((address_space(1))) void*)(gp),                         \
    (__attribute__((address_space(3))) void*)(lp), 16, 0, 0)

// ---- dtype detection ----
__global__ void k_detect(const void* feat, const void* gi) {
  __shared__ int cnt;
  if (threadIdx.x == 0) cnt = 0;
  __syncthreads();
  u16 u = ((const u16*)feat)[threadIdx.x];
  float v = bf2f(u);
  float a = fabsf(v);
  int ok = (v == v) && a >= 1e-6f && a <= 1e6f;
  atomicAdd(&cnt, ok);
  __syncthreads();
  if (threadIdx.x == 0) {
    g_isbf16 = (cnt >= 230);
    g_idx64 = (((const int*)gi)[N_NODES - 1] == 0);
  }
}

// ---- conversions (pair-indexed): features->fp16, W_m->fp16, W_m^T, Wg ----
#define NFP ((size_t)N_NODES * DIM / 2)
#define NWP ((size_t)HD * DIM / 2)
#define NWT ((size_t)DIM * HD / 2)
#define NWG ((size_t)2048 * 1024 / 2)
__global__ __launch_bounds__(256) void k_cvt_all(const void* f, const void* wm,
                                                 const void* wih, const void* whh) {
  const int isb = g_isbf16;
  size_t i = (size_t)blockIdx.x * 256 + threadIdx.x;
  if (i < NFP + NWP) {
    const void* src = (i < NFP) ? f : wm;
    u16* dst = (i < NFP) ? g_fb : g_wm;
    size_t off = (i < NFP) ? i : i - NFP;
    float v0, v1;
    if (isb) {
      unsigned pr = ((const unsigned*)src)[off];
      v0 = bf2f((u16)pr); v1 = bf2f((u16)(pr >> 16));
    } else {
      float2 v = ((const float2*)src)[off];
      v0 = v.x; v1 = v.y;
    }
    ((unsigned*)dst)[off] = (unsigned)f2h(v0) | ((unsigned)f2h(v1) << 16);
  } else if (i < NFP + NWP + NWT) {
    size_t p = i - NFP - NWP;
    int d = (int)(p >> 8), j = (int)(p & 255) * 2;   // wmT[d][j], wmT[d][j+1]
    float v0 = rdf(wm, j * DIM + d);
    float v1 = rdf(wm, (j + 1) * DIM + d);
    ((unsigned*)g_wmT)[(size_t)d * (HD / 2) + (j >> 1)] =
        (unsigned)f2h(v0) | ((unsigned)f2h(v1) << 16);
  } else if (i < NFP + NWP + NWT + NWG) {
    size_t off = i - NFP - NWP - NWT;
    int n = (int)(off >> 9), kp = (int)(off & 511);
    int k = kp * 2;
    float v0 = rdf(wih, n * 1024 + k);
    float v1 = rdf(wih, n * 1024 + k + 1);
    if (k < 512) {
      v0 += rdf(whh, n * 512 + k);
      v1 += rdf(whh, n * 512 + k + 1);
    }
    ((unsigned*)g_wg)[off] = (unsigned)f2h(v0) | ((unsigned)f2h(v1) << 16);
  }
}
#define CVT_BLOCKS ((int)((NFP + NWP + NWT + NWG + 255) / 256))

// ---- zero-init: Acat (1,048,576 dwords) + c (1,048,576 floats) ----
__global__ void k_init() {
  int i = blockIdx.x * 256 + threadIdx.x;            // grid 4096*256
  ((unsigned*)g_Acat)[i] = 0u;
  g_c[i] = 0.f;
}

// ---- per-graph start offsets from sorted graph_index ----
__global__ void k_offsets(const void* giv) {
  int n = blockIdx.x * 256 + threadIdx.x;
  if (n >= N_NODES) return;
  const int idx64 = g_idx64;
  int g = idx64 ? (int)((const long long*)giv)[n] : ((const int*)giv)[n];
  if (n == 0) {
    for (int x = 0; x <= g; ++x) g_start[x] = 0;
  } else {
    int gp = idx64 ? (int)((const long long*)giv)[n - 1] : ((const int*)giv)[n - 1];
    for (int x = gp + 1; x <= g; ++x) g_start[x] = n;
  }
  if (n == N_NODES - 1) {
    for (int x = g + 1; x <= NG; ++x) g_start[x] = N_NODES;
  }
}

// ---- GEMM: gates = [h|r] @ Wg^T  (M=2048,N=2048,K=1024), 64x64 tiles,
// two K-tiles per barrier (double LDS buffer) ----
__global__ __launch_bounds__(256) void k_gemm_gates() {
  __shared__ u16 As[2][64 * 64];                     // 2x8 KB, XOR-swizzled
  __shared__ u16 Bs[2][64 * 64];
  const int t = threadIdx.x, lid = t & 63, w = t >> 6;
  const int m0 = blockIdx.x * 64, n0 = blockIdx.y * 64;
  const int rr = lid & 15, quad = lid >> 4;
  const int rsub = lid >> 3;                         // 0..7
  const int cs = (lid & 7) ^ rsub;                   // swizzled k-chunk
  const int wm = (w >> 1) * 32, wn = (w & 1) * 32;
  f32x4 acc[2][2] = {};
  for (int kt2 = 0; kt2 < 8; ++kt2) {
#pragma unroll
    for (int b = 0; b < 2; ++b) {
      const int k0 = (kt2 * 2 + b) * 64;
      GLD16(g_Acat + (size_t)(m0 + w * 16 + rsub) * 1024 + k0 + cs * 8, As[b] + (w * 16) * 64);
      GLD16(g_Acat + (size_t)(m0 + w * 16 + 8 + rsub) * 1024 + k0 + cs * 8, As[b] + (w * 16 + 8) * 64);
      GLD16(g_wg   + (size_t)(n0 + w * 16 + rsub) * 1024 + k0 + cs * 8, Bs[b] + (w * 16) * 64);
      GLD16(g_wg   + (size_t)(n0 + w * 16 + 8 + rsub) * 1024 + k0 + cs * 8, Bs[b] + (w * 16 + 8) * 64);
    }
    __syncthreads();
#pragma unroll
    for (int b = 0; b < 2; ++b)
#pragma unroll
      for (int kk = 0; kk < 2; ++kk) {
        const int qb = kk * 4 + quad;
        const int sw = (qb ^ (rr & 7)) << 3;
        half8 af[2], bfr[2];
#pragma unroll
        for (int i = 0; i < 2; ++i) af[i]  = *(const half8*)(As[b] + (wm + i * 16 + rr) * 64 + sw);
#pragma unroll
        for (int j = 0; j < 2; ++j) bfr[j] = *(const half8*)(Bs[b] + (wn + j * 16 + rr) * 64 + sw);
#pragma unroll
        for (int i = 0; i < 2; ++i)
#pragma unroll
          for (int j = 0; j < 2; ++j)
            acc[i][j] = __builtin_amdgcn_mfma_f32_16x16x32_f16(bfr[j], af[i], acc[i][j], 0, 0, 0);
      }
    __syncthreads();
  }
#pragma unroll
  for (int i = 0; i < 2; ++i)
#pragma unroll
    for (int j = 0; j < 2; ++j) {
      const int row = m0 + wm + i * 16 + rr;
      const int c0 = n0 + wn + j * 16 + quad * 4;
      *(f32x4*)(g_gates + (size_t)row * 2048 + c0) = acc[i][j];
    }
}

// ---- GEMM: W2 = h @ W_m  (M=2048, N=128, K=512), 64x64 tiles ----
__global__ __launch_bounds__(256) void k_w2() {
  __shared__ u16 As[64 * 64];
  __shared__ u16 Bs[64 * 64];
  const int t = threadIdx.x, lid = t & 63, w = t >> 6;
  const int m0 = blockIdx.x * 64, n0 = blockIdx.y * 64;
  const int rr = lid & 15, quad = lid >> 4;
  const int rsub = lid >> 3;
  const int cs = (lid & 7) ^ rsub;
  const int wm = (w >> 1) * 32, wn = (w & 1) * 32;
  f32x4 acc[2][2] = {};
  for (int kt = 0; kt < 8; ++kt) {
    const int k0 = kt * 64;
    GLD16(g_Acat + (size_t)(m0 + w * 16 + rsub) * 1024 + k0 + cs * 8, As + (w * 16) * 64);
    GLD16(g_Acat + (size_t)(m0 + w * 16 + 8 + rsub) * 1024 + k0 + cs * 8, As + (w * 16 + 8) * 64);
    GLD16(g_wmT  + (size_t)(n0 + w * 16 + rsub) * 512 + k0 + cs * 8, Bs + (w * 16) * 64);
    GLD16(g_wmT  + (size_t)(n0 + w * 16 + 8 + rsub) * 512 + k0 + cs * 8, Bs + (w * 16 + 8) * 64);
    __syncthreads();
#pragma unroll
    for (int kk = 0; kk < 2; ++kk) {
      const int qb = kk * 4 + quad;
      const int sw = (qb ^ (rr & 7)) << 3;
      half8 af[2], bfr[2];
#pragma unroll
      for (int i = 0; i < 2; ++i) af[i]  = *(const half8*)(As + (wm + i * 16 + rr) * 64 + sw);
#pragma unroll
      for (int j = 0; j < 2; ++j) bfr[j] = *(const half8*)(Bs + (wn + j * 16 + rr) * 64 + sw);
#pragma unroll
      for (int i = 0; i < 2; ++i)
#pragma unroll
        for (int j = 0; j < 2; ++j)
          acc[i][j] = __builtin_amdgcn_mfma_f32_16x16x32_f16(bfr[j], af[i], acc[i][j], 0, 0, 0);
    }
    __syncthreads();
  }
#pragma unroll
  for (int i = 0; i < 2; ++i)
#pragma unroll
    for (int j = 0; j < 2; ++j) {
      const int row = m0 + wm + i * 16 + rr;
      const int c0 = n0 + wn + j * 16 + quad * 4;
      *(f32x4*)(g_w2 + (size_t)row * DIM + c0) = acc[i][j];
    }
}

// ---- LSTM cell elementwise ----
__global__ __launch_bounds__(256) void k_lstm(const void* __restrict__ b_ih,
                                              const void* __restrict__ b_hh,
                                              void* __restrict__ out, int wout) {
  int idx = blockIdx.x * 256 + threadIdx.x;          // NG*HD threads
  int g = idx >> 9, j = idx & 511;
  const float* grow = g_gates + (size_t)g * 2048;
  float xi = grow[j]        + rdf(b_ih, j)        + rdf(b_hh, j);
  float xf = grow[j + 512]  + rdf(b_ih, j + 512)  + rdf(b_hh, j + 512);
  float xg = grow[j + 1024] + rdf(b_ih, j + 1024) + rdf(b_hh, j + 1024);
  float xo = grow[j + 1536] + rdf(b_ih, j + 1536) + rdf(b_hh, j + 1536);
  float si = 1.f / (1.f + __expf(-xi));
  float sf = 1.f / (1.f + __expf(-xf));
  float tg = tanhf(xg);
  float so = 1.f / (1.f + __expf(-xo));
  float cn = sf * g_c[idx] + si * tg;
  float hn = so * tanhf(cn);
  g_c[idx] = cn;
  g_Acat[(size_t)g * 1024 + j] = f2h(hn);
  if (wout) {
    if (g_isbf16) ((u16*)out)[(size_t)g * 1024 + j] = f2bf(hn);
    else          ((float*)out)[(size_t)g * 1024 + j] = hn;
  }
}

// ---- attention scores+softmax+weighted feature sum. One block per graph.
// Writes S' = sum(a_n f_n) fp16 [NG x 128] and t' = sum(a_n) fp32 [NG].
__global__ __launch_bounds__(256) void k_attn_s() {
  const int g = blockIdx.x;
  const int t = threadIdx.x, lid = t & 63, wid = t >> 6;
  const int c = lid & 15;                            // 8-col chunk index
  const int slot = lid >> 4;                         // node slot 0..3
  __shared__ float s_m[4], s_l[4];
  __shared__ float s_s[4][DIM];
  const int s = g_start[g], e = g_start[g + 1];
  float w2r[8];
  *(float4*)(w2r)     = *(const float4*)(g_w2 + (size_t)g * DIM + c * 8);
  *(float4*)(w2r + 4) = *(const float4*)(g_w2 + (size_t)g * DIM + c * 8 + 4);
  float mrun = -3.0e38f, lsum = 0.f;
  float racc[8] = {0.f, 0.f, 0.f, 0.f, 0.f, 0.f, 0.f, 0.f};
  for (int nb = s + wid * 4; nb < e; nb += 16) {     // 4 waves x 4 slots
    const int n = nb + slot;
    float fv[8], d;
    if (n < e) {
      half8 hv = *(const half8*)(g_fb + (size_t)n * DIM + c * 8);
      d = 0.f;
#pragma unroll
      for (int j = 0; j < 8; ++j) { fv[j] = (float)hv[j]; d += fv[j] * w2r[j]; }
    } else {
      d = -1.0e30f;                                  // poison: slot inactive
#pragma unroll
      for (int j = 0; j < 8; ++j) fv[j] = 0.f;
    }
#pragma unroll
    for (int o = 1; o < 16; o <<= 1) d += __shfl_xor(d, o, 64);
    float m4 = fmaxf(d, __shfl_xor(d, 16, 64));
    m4 = fmaxf(m4, __shfl_xor(m4, 32, 64));
    float mnew = fmaxf(mrun, m4);
    float sc = __expf(mrun - mnew);
    float w = __expf(d - mnew);
    lsum = lsum * sc + w;
#pragma unroll
    for (int j = 0; j < 8; ++j) racc[j] = racc[j] * sc + w * fv[j];
    mrun = mnew;
  }
  float lt = lsum + __shfl_xor(lsum, 16, 64);
  lt += __shfl_xor(lt, 32, 64);
#pragma unroll
  for (int j = 0; j < 8; ++j) {
    racc[j] += __shfl_xor(racc[j], 16, 64);
    racc[j] += __shfl_xor(racc[j], 32, 64);
  }
  if (lid == 0) s_m[wid] = mrun;
  __syncthreads();
  float gmax = fmaxf(fmaxf(s_m[0], s_m[1]), fmaxf(s_m[2], s_m[3]));
  float scw = __expf(mrun - gmax);                   // wave-uniform
  if (lid < 16) {
    float4 lo = make_float4(racc[0] * scw, racc[1] * scw, racc[2] * scw, racc[3] * scw);
    float4 hi = make_float4(racc[4] * scw, racc[5] * scw, racc[6] * scw, racc[7] * scw);
    *(float4*)&s_s[wid][c * 8] = lo;
    *(float4*)&s_s[wid][c * 8 + 4] = hi;
  }
  if (lid == 0) s_l[wid] = lt * scw;
  __syncthreads();
  float total = s_l[0] + s_l[1] + s_l[2] + s_l[3];
  float inv = 1.f / (total + 1e-7f);
  if (t == 0) g_tp[g] = total * inv;
  if (t < 64) {
    int d0 = t * 2;
    float v0 = (s_s[0][d0] + s_s[1][d0] + s_s[2][d0] + s_s[3][d0]) * inv;
    float v1 = (s_s[0][d0 + 1] + s_s[1][d0 + 1] + s_s[2][d0 + 1] + s_s[3][d0 + 1]) * inv;
    ((unsigned*)g_sp)[(size_t)g * 64 + t] = (unsigned)f2h(v0) | ((unsigned)f2h(v1) << 16);
  }
}

// ---- GEMM: r = S' @ W_m^T + t'*b_m  (M=2048, N=512, K=128), 64x64 tiles ----
__global__ __launch_bounds__(256) void k_r(const void* __restrict__ bias,
                                           void* __restrict__ out, int wout) {
  __shared__ u16 As[64 * 64];
  __shared__ u16 Bs[64 * 64];
  const int t = threadIdx.x, lid = t & 63, w = t >> 6;
  const int m0 = blockIdx.x * 64, n0 = blockIdx.y * 64;
  const int rr = lid & 15, quad = lid >> 4;
  const int rsub = lid >> 3;
  const int cs = (lid & 7) ^ rsub;
  const int wm = (w >> 1) * 32, wn = (w & 1) * 32;
  f32x4 acc[2][2] = {};
  for (int kt = 0; kt < 2; ++kt) {
    const int k0 = kt * 64;
    GLD16(g_sp + (size_t)(m0 + w * 16 + rsub) * 128 + k0 + cs * 8, As + (w * 16) * 64);
    GLD16(g_sp + (size_t)(m0 + w * 16 + 8 + rsub) * 128 + k0 + cs * 8, As + (w * 16 + 8) * 64);
    GLD16(g_wm + (size_t)(n0 + w * 16 + rsub) * 128 + k0 + cs * 8, Bs + (w * 16) * 64);
    GLD16(g_wm + (size_t)(n0 + w * 16 + 8 + rsub) * 128 + k0 + cs * 8, Bs + (w * 16 + 8) * 64);
    __syncthreads();
#pragma unroll
    for (int kk = 0; kk < 2; ++kk) {
      const int qb = kk * 4 + quad;
      const int sw = (qb ^ (rr & 7)) << 3;
      half8 af[2], bfr[2];
#pragma unroll
      for (int i = 0; i < 2; ++i) af[i]  = *(const half8*)(As + (wm + i * 16 + rr) * 64 + sw);
#pragma unroll
      for (int j = 0; j < 2; ++j) bfr[j] = *(const half8*)(Bs + (wn + j * 16 + rr) * 64 + sw);
#pragma unroll
      for (int i = 0; i < 2; ++i)
#pragma unroll
        for (int j = 0; j < 2; ++j)
          acc[i][j] = __builtin_amdgcn_mfma_f32_16x16x32_f16(bfr[j], af[i], acc[i][j], 0, 0, 0);
    }
    __syncthreads();
  }
  const int isb = g_isbf16;
#pragma unroll
  for (int i = 0; i < 2; ++i) {
    const int row = m0 + wm + i * 16 + rr;           // graph
    const float tp = g_tp[row];
#pragma unroll
    for (int j = 0; j < 2; ++j) {
      const int c0 = n0 + wn + j * 16 + quad * 4;    // output col
      u16 h4[4]; float rv[4];
#pragma unroll
      for (int r = 0; r < 4; ++r) {
        rv[r] = acc[i][j][r] + tp * rdf(bias, c0 + r);
        h4[r] = f2h(rv[r]);
      }
      *(uint2*)(g_Acat + (size_t)row * 1024 + 512 + c0) =
          make_uint2((unsigned)h4[0] | ((unsigned)h4[1] << 16),
                     (unsigned)h4[2] | ((unsigned)h4[3] << 16));
      if (wout) {
        if (isb) {
          u16 b4[4];
#pragma unroll
          for (int r = 0; r < 4; ++r) b4[r] = f2bf(rv[r]);
          *(uint2*)((u16*)out + (size_t)row * 1024 + 512 + c0) =
              make_uint2((unsigned)b4[0] | ((unsigned)b4[1] << 16),
                         (unsigned)b4[2] | ((unsigned)b4[3] << 16));
        } else {
          *(f32x4*)((float*)out + (size_t)row * 1024 + 512 + c0) =
              *(f32x4*)rv;
        }
      }
    }
  }
}

extern "C" void kernel_launch(void* const* d_in, const int* in_sizes, int n_in,
                              void* d_out, int out_size, void* d_ws, size_t ws_size,
                              hipStream_t stream) {
  const void* features = d_in[0];
  const void* gidx     = d_in[1];
  const void* W_m      = d_in[2];
  const void* b_m      = d_in[3];
  const void* W_ih     = d_in[4];
  const void* W_hh     = d_in[5];
  const void* b_ih     = d_in[6];
  const void* b_hh     = d_in[7];

  k_detect<<<1, 256, 0, stream>>>(features, gidx);
  k_cvt_all<<<CVT_BLOCKS, 256, 0, stream>>>(features, W_m, W_ih, W_hh);
  k_init<<<4096, 256, 0, stream>>>();
  k_offsets<<<N_NODES / 256, 256, 0, stream>>>(gidx);
  for (int loop = 0; loop < 3; ++loop) {
    const int wout = (loop == 2);
    k_gemm_gates<<<dim3(32, 32), 256, 0, stream>>>();
    k_lstm<<<NG * HD / 256, 256, 0, stream>>>(b_ih, b_hh, d_out, wout);
    k_w2<<<dim3(32, 2), 256, 0, stream>>>();
    k_attn_s<<<NG, 256, 0, stream>>>();
    k_r<<<dim3(32, 8), 256, 0, stream>>>(b_m, d_out, wout);
  }
}